// Round 6
// baseline (1187.016 us; speedup 1.0000x reference)
//
#include <hip/hip_runtime.h>
#include <hip/hip_cooperative_groups.h>
#include <cstdint>

#define NODES 2100

typedef __attribute__((ext_vector_type(8))) __bf16 bf16x8;
typedef __attribute__((ext_vector_type(4))) float f32x4;
typedef __attribute__((ext_vector_type(8))) unsigned short u16x8;

__device__ inline float bf2f(unsigned short s) { return __uint_as_float(((unsigned)s) << 16); }
__device__ inline unsigned short f2bf(float f) {
    unsigned u = __float_as_uint(f);
    u += 0x7fff + ((u >> 16) & 1);          // RNE
    return (unsigned short)(u >> 16);
}
__device__ inline void gload16(const unsigned short* g, void* lds) {
    __builtin_amdgcn_global_load_lds(
        (const __attribute__((address_space(1))) void*)g,
        (__attribute__((address_space(3))) void*)lds, 16, 0, 0);
}

// grid-strided float4 copy over the first `nb` blocks of a launch
__device__ inline void copy_chunk(const float4* __restrict__ s, float4* __restrict__ d,
                                  int nquads, int bid, int nb)
{
    for (int i = bid * 256 + threadIdx.x; i < nquads; i += nb * 256) d[i] = s[i];
}

// ---------------------------------------------------------------------------
// Shared MFMA GEMM core (convt), 128x128 tile, BK=64, XOR-swizzled LDS
// both sides (linear dest + pre-swizzled source + swizzled read).
// ---------------------------------------------------------------------------
__device__ __attribute__((always_inline)) inline
void gemm_core(const unsigned short* __restrict__ A, const unsigned short* __restrict__ B,
               int K, int m0, int n0, int mClamp, int nClamp,
               unsigned short* As, unsigned short* Bs, f32x4 acc[4][4])
{
    const int t = threadIdx.x, lane = t & 63, w = t >> 6;
    const int wr = w >> 1, wc = w & 1;
    const int sx = (lane & 7) << 4;
    for (int k0 = 0; k0 < K; k0 += 64) {
#pragma unroll
        for (int i = 0; i < 4; ++i) {
            int LO  = ((i << 8) + t) << 4;
            int row = LO >> 7;
            int kb  = (LO & 127) ^ ((row & 7) << 4);
            int ke  = kb >> 1;
            int ra = m0 + row; if (ra > mClamp) ra = mClamp;
            int rb = n0 + row; if (rb > nClamp) rb = nClamp;
            gload16(A + (size_t)ra * K + k0 + ke, (char*)As + LO);
            gload16(B + (size_t)rb * K + k0 + ke, (char*)Bs + LO);
        }
        asm volatile("s_waitcnt vmcnt(0)" ::: "memory");
        __syncthreads();
#pragma unroll
        for (int kk = 0; kk < 2; ++kk) {
            bf16x8 a[4], bb[4];
#pragma unroll
            for (int f = 0; f < 4; ++f) {
                int pa = (((wr * 64 + f * 16 + (lane & 15)) << 7) + kk * 64 + ((lane >> 4) << 4)) ^ sx;
                int pb = (((wc * 64 + f * 16 + (lane & 15)) << 7) + kk * 64 + ((lane >> 4) << 4)) ^ sx;
                a[f]  = *(const bf16x8*)((const char*)As + pa);
                bb[f] = *(const bf16x8*)((const char*)Bs + pb);
            }
#pragma unroll
            for (int fr = 0; fr < 4; ++fr)
#pragma unroll
                for (int fc = 0; fc < 4; ++fc)
                    acc[fr][fc] = __builtin_amdgcn_mfma_f32_16x16x32_bf16(a[fr], bb[fc], acc[fr][fc], 0, 0, 0);
        }
        __syncthreads();
    }
}

// ---------------------------------------------------------------------------
// mega-prep: weight conversions/transposes + BN scale/shift, one launch
// ---------------------------------------------------------------------------
struct PrepArgs {
    const float *dw0, *dw1, *dw2;
    const float *gw0, *gw1, *gw2, *gw3, *gw4, *gw5;
    const float *tw0, *tw1, *tw2;
    const float *g0, *g1, *g2, *b0, *b1, *b2, *m0, *m1, *m2, *v0, *v1, *v2, *db0, *db1, *db2;
    unsigned short *dwb, *gWTb, *tWTb;
    float *scshb;
};

__device__ inline void transpose32(const float* __restrict__ in, unsigned short* __restrict__ outT,
                                   int Ccols, int c0, int r0)
{
    __shared__ float T[32][33];
    const int tx = threadIdx.x & 31, ty = threadIdx.x >> 5;
#pragma unroll
    for (int i = 0; i < 4; ++i)
        T[ty + i * 8][tx] = in[(size_t)(r0 + ty + i * 8) * Ccols + c0 + tx];
    __syncthreads();
#pragma unroll
    for (int i = 0; i < 4; ++i)
        outT[(size_t)(c0 + ty + i * 8) * 256 + r0 + tx] = f2bf(T[tx][ty + i * 8]);
}

__global__ __launch_bounds__(256)
void mega_prep(PrepArgs a)
{
    int bid = blockIdx.x;
    const int t = threadIdx.x;
    if (bid < 448) {                           // dw convert (concatenated)
        int idx = (bid * 256 + t) * 8;
        const float* src;
        int loc;
        if (idx < 131072)      { src = a.dw0; loc = idx; }
        else if (idx < 393216) { src = a.dw1; loc = idx - 131072; }
        else                   { src = a.dw2; loc = idx - 393216; }
        float4 x = *(const float4*)(src + loc);
        float4 y = *(const float4*)(src + loc + 4);
        u16x8 r;
        r[0] = f2bf(x.x); r[1] = f2bf(x.y); r[2] = f2bf(x.z); r[3] = f2bf(x.w);
        r[4] = f2bf(y.x); r[5] = f2bf(y.y); r[6] = f2bf(y.z); r[7] = f2bf(y.w);
        *(u16x8*)(a.dwb + idx) = r;
    } else if (bid < 832) {                    // gW transpose: 6 x (8x8 blocks)
        int gid = bid - 448;
        int l = gid >> 6, sb = gid & 63;
        const float* gw[6] = {a.gw0, a.gw1, a.gw2, a.gw3, a.gw4, a.gw5};
        transpose32(gw[l], a.gWTb + (size_t)l * 65536, 256, (sb & 7) << 5, (sb >> 3) << 5);
    } else if (bid < 4416) {                   // tW transpose
        int gid = bid - 832;
        const float* tw; unsigned short* dst; int ncx, loc;
        if (gid < 512)       { tw = a.tw0; dst = a.tWTb;           ncx = 64;  loc = gid; }
        else if (gid < 1536) { tw = a.tw1; dst = a.tWTb + 524288;  ncx = 128; loc = gid - 512; }
        else                 { tw = a.tw2; dst = a.tWTb + 1572864; ncx = 256; loc = gid - 1536; }
        int cx = loc % ncx, ry = loc / ncx;
        transpose32(tw, dst, ncx * 32, cx << 5, ry << 5);
    } else {                                   // BN scale/shift
        const float* g[3]  = {a.g0, a.g1, a.g2};
        const float* b[3]  = {a.b0, a.b1, a.b2};
        const float* m[3]  = {a.m0, a.m1, a.m2};
        const float* v[3]  = {a.v0, a.v1, a.v2};
        const float* db[3] = {a.db0, a.db1, a.db2};
        for (int s = 0; s < 3; ++s) {
            float sc = g[s][t] * rsqrtf(v[s][t] + 1e-5f);
            a.scshb[s * 512 + t] = sc;
            a.scshb[s * 512 + 256 + t] = (db[s][t] - m[s][t]) * sc + b[s][t];
        }
    }
}

// ---------------------------------------------------------------------------
// Fused conv1x1: transpose-stage fp32 feat into swizzled LDS, MFMA vs
// weights (BM=64 x BN=256, all scales, one launch), BN+ReLU+pool epilogue.
// ---------------------------------------------------------------------------
struct ConvArgs {
    const float* feat[3];
    const unsigned short* dwb[3];
    const float* scsh[3];
    unsigned short* h0out;
};

__global__ __launch_bounds__(256)
void conv_fused(ConvArgs ca)
{
    __shared__ __align__(16) unsigned short As[64 * 64];   // swizzled, 8 KB
    __shared__ __align__(16) unsigned short Bs[256 * 64];  // swizzled, 32 KB
    int bx = blockIdx.x;
    int s, mt;
    if (bx < 800)       { s = 0; mt = bx; }
    else if (bx < 1000) { s = 1; mt = bx - 800; }
    else                { s = 2; mt = bx - 1000; }
    const int Kc[3]  = {512, 1024, 2048};
    const int Wc[3]  = {80, 40, 20};
    const int PPc[3] = {1600, 400, 100};
    const int nfc[3] = {0, 1600, 2000};
    const int K = Kc[s], W = Wc[s], W2 = W >> 1, HW = W * W, PP = PPc[s], noff = nfc[s];
    const float* feat = ca.feat[s];
    const unsigned short* dw = ca.dwb[s];
    const float* scsh = ca.scsh[s];

    const int t = threadIdx.x, lane = t & 63, w = t >> 6;
    const int sx = (lane & 7) << 4;

    const int ml = t & 63;
    const int kw = t >> 6;
    const int graw = mt * 64 + ml;
    const int b = graw / HW;
    const int rem = graw - b * HW;
    const int pooled = rem >> 2, sub = rem & 3;
    const int pi = pooled / W2, pj = pooled - pi * W2;
    const int i = pi * 2 + (sub >> 1), j = pj * 2 + (sub & 1);
    const float* src = feat + (size_t)b * K * HW + (size_t)i * W + j;
    const int sxm = (ml & 7) << 3;

    f32x4 acc[4][4];
#pragma unroll
    for (int fr = 0; fr < 4; ++fr)
#pragma unroll
        for (int fc = 0; fc < 4; ++fc) acc[fr][fc] = (f32x4){0.f, 0.f, 0.f, 0.f};

    for (int k0 = 0; k0 < K; k0 += 64) {
#pragma unroll
        for (int it = 0; it < 8; ++it) {
            int LO = ((it << 8) + t) << 4;
            int row = LO >> 7;
            int kb = (LO & 127) ^ ((row & 7) << 4);
            gload16(dw + (size_t)row * K + k0 + (kb >> 1), (char*)Bs + LO);
        }
        float v[16];
#pragma unroll
        for (int it = 0; it < 16; ++it)
            v[it] = src[(size_t)(k0 + it * 4 + kw) * HW];
#pragma unroll
        for (int it = 0; it < 16; ++it) {
            int k_l = it * 4 + kw;
            As[(ml << 6) + (k_l ^ sxm)] = f2bf(v[it]);
        }
        asm volatile("s_waitcnt vmcnt(0)" ::: "memory");
        __syncthreads();
#pragma unroll
        for (int kk = 0; kk < 2; ++kk) {
            bf16x8 a[4], bb[4];
#pragma unroll
            for (int f = 0; f < 4; ++f) {
                int pa = (((f * 16 + (lane & 15)) << 7) + kk * 64 + ((lane >> 4) << 4)) ^ sx;
                int pb = (((w * 64 + f * 16 + (lane & 15)) << 7) + kk * 64 + ((lane >> 4) << 4)) ^ sx;
                a[f]  = *(const bf16x8*)((const char*)As + pa);
                bb[f] = *(const bf16x8*)((const char*)Bs + pb);
            }
#pragma unroll
            for (int fr = 0; fr < 4; ++fr)
#pragma unroll
                for (int fc = 0; fc < 4; ++fc)
                    acc[fr][fc] = __builtin_amdgcn_mfma_f32_16x16x32_bf16(a[fr], bb[fc], acc[fr][fc], 0, 0, 0);
        }
        __syncthreads();
    }

#pragma unroll
    for (int fc = 0; fc < 4; ++fc) {
        const int o = w * 64 + fc * 16 + (lane & 15);
        const float sc = scsh[o], sh = scsh[256 + o];
#pragma unroll
        for (int fr = 0; fr < 4; ++fr) {
            const int mrow = mt * 64 + fr * 16 + (lane >> 4) * 4;
            const int q = mrow >> 2;
            const int bi = q / PP;
            const int node = noff + (q - bi * PP);
            float sum = 0.f;
#pragma unroll
            for (int r = 0; r < 4; ++r)
                sum += fmaxf(acc[fr][fc][r] * sc + sh, 0.f);
            ca.h0out[((size_t)(bi * NODES + node)) * 256 + o] = f2bf(sum * 0.25f);
        }
    }
}

// ---------------------------------------------------------------------------
// ALL 6 GNN layers in ONE cooperative kernel.  grid=512 blocks (36 KB LDS
// -> >=2 blocks/CU co-resident), strip-strided over 525 strips of 32 rows,
// __threadfence + grid.sync between layers.  Gather software-pipelined.
// ---------------------------------------------------------------------------
struct GnnAllArgs {
    const unsigned short* h0;
    unsigned short* bufA;
    unsigned short* bufB;
    const unsigned short* WT;    // 6 * 65536 bf16
    const float *gb0, *gb1, *gb2, *gb3, *gb4, *gb5;
};

__global__ __launch_bounds__(256)
void gnn_all(GnnAllArgs a)
{
    __shared__ __align__(16) unsigned short As[32 * 64];   // swizzled, 4 KB
    __shared__ __align__(16) unsigned short Bs[256 * 64];  // swizzled, 32 KB
    cooperative_groups::grid_group grid = cooperative_groups::this_grid();
    const int t = threadIdx.x, lane = t & 63, w = t >> 6;
    const int sx = (lane & 7) << 4;
    const unsigned short* hin = a.h0;

    for (int l = 0; l < 6; ++l) {
        unsigned short* out = (l & 1) ? a.bufB : a.bufA;
        const unsigned short* BT = a.WT + (size_t)l * 65536;
        const float* bias = (l == 0) ? a.gb0 : (l == 1) ? a.gb1 : (l == 2) ? a.gb2
                          : (l == 3) ? a.gb3 : (l == 4) ? a.gb4 : a.gb5;
        const int hier = (l == 2 || l == 3);

        for (int strip = blockIdx.x; strip < 525; strip += gridDim.x) {
            const int r0 = strip << 5;
            const int myrow = t >> 3, q = t & 7;      // 8 threads/row, 8 k each
            const int grow = r0 + myrow;
            const int b = grow / NODES;
            const int n = grow - b * NODES;

            int gw, off;
            if (n < 1600)      { gw = 40; off = 0; }
            else if (n < 2000) { gw = 20; off = 1600; }
            else               { gw = 10; off = 2000; }
            const int li = (n - off) / gw;
            const int lj = (n - off) - li * gw;
            int nbr[9]; int cnt = 0;
            if (!hier) {
#pragma unroll
                for (int di = -1; di <= 1; ++di)
#pragma unroll
                    for (int dj = -1; dj <= 1; ++dj) {
                        int ii = li + di, jj = lj + dj;
                        if (ii >= 0 && ii < gw && jj >= 0 && jj < gw) nbr[cnt++] = off + ii * gw + jj;
                    }
            } else {
                nbr[cnt++] = n;
                if (off == 0) {
                    nbr[cnt++] = 1600 + (li >> 1) * 20 + (lj >> 1);
                } else if (off == 1600) {
                    nbr[cnt++] = 2000 + (li >> 1) * 10 + (lj >> 1);
#pragma unroll
                    for (int di = 0; di < 2; ++di)
#pragma unroll
                        for (int dj = 0; dj < 2; ++dj)
                            nbr[cnt++] = ((li << 1) + di) * 40 + ((lj << 1) + dj);
                } else {
#pragma unroll
                    for (int di = 0; di < 2; ++di)
#pragma unroll
                        for (int dj = 0; dj < 2; ++dj)
                            nbr[cnt++] = 1600 + ((li << 1) + di) * 20 + ((lj << 1) + dj);
                }
            }
            int nboff[9];
#pragma unroll
            for (int e = 0; e < 9; ++e)
                nboff[e] = (b * NODES + nbr[e < cnt ? e : 0]) * 256 + q * 8;
            const float inv = 1.0f / (float)cnt;
            const int awr = (myrow << 6) + ((q ^ (myrow & 7)) << 3);  // swizzled slot

            f32x4 acc[2][4];
#pragma unroll
            for (int fr = 0; fr < 2; ++fr)
#pragma unroll
                for (int fc = 0; fc < 4; ++fc) acc[fr][fc] = (f32x4){0.f, 0.f, 0.f, 0.f};

            // prefetch gather for k0 = 0
            u16x8 pre[9];
#pragma unroll
            for (int e = 0; e < 9; ++e) pre[e] = *(const u16x8*)(hin + nboff[e]);

            for (int k0 = 0; k0 < 256; k0 += 64) {
                // B stage (weights, swizzled source)
#pragma unroll
                for (int it = 0; it < 8; ++it) {
                    int LO = ((it << 8) + t) << 4;
                    int row = LO >> 7;
                    int kb = (LO & 127) ^ ((row & 7) << 4);
                    gload16(BT + (size_t)row * 256 + k0 + (kb >> 1), (char*)Bs + LO);
                }
                // accumulate current prefetched gather
                float sacc[8] = {0, 0, 0, 0, 0, 0, 0, 0};
#pragma unroll
                for (int e = 0; e < 9; ++e) {
                    if (e < cnt) {
#pragma unroll
                        for (int jj = 0; jj < 8; ++jj) sacc[jj] += bf2f(pre[e][jj]);
                    }
                }
                u16x8 o0;
#pragma unroll
                for (int jj = 0; jj < 8; ++jj) o0[jj] = f2bf(sacc[jj] * inv);
                *(u16x8*)&As[awr] = o0;

                asm volatile("s_waitcnt vmcnt(0)" ::: "memory");
                __syncthreads();

                // prefetch next k-step's gather; in flight during MFMA
                const int k0n = (k0 + 64) & 255;
#pragma unroll
                for (int e = 0; e < 9; ++e) pre[e] = *(const u16x8*)(hin + nboff[e] + k0n);

#pragma unroll
                for (int kk = 0; kk < 2; ++kk) {
                    bf16x8 av[2], bb[4];
#pragma unroll
                    for (int f = 0; f < 2; ++f) {
                        int pa = (((f * 16 + (lane & 15)) << 7) + kk * 64 + ((lane >> 4) << 4)) ^ sx;
                        av[f] = *(const bf16x8*)((const char*)As + pa);
                    }
#pragma unroll
                    for (int f = 0; f < 4; ++f) {
                        int pb = (((w * 64 + f * 16 + (lane & 15)) << 7) + kk * 64 + ((lane >> 4) << 4)) ^ sx;
                        bb[f] = *(const bf16x8*)((const char*)Bs + pb);
                    }
#pragma unroll
                    for (int fr = 0; fr < 2; ++fr)
#pragma unroll
                        for (int fc = 0; fc < 4; ++fc)
                            acc[fr][fc] = __builtin_amdgcn_mfma_f32_16x16x32_bf16(av[fr], bb[fc], acc[fr][fc], 0, 0, 0);
                }
                __syncthreads();
            }

#pragma unroll
            for (int fc = 0; fc < 4; ++fc) {
                const int d = w * 64 + fc * 16 + (lane & 15);
                const float bv = bias[d];
#pragma unroll
                for (int fr = 0; fr < 2; ++fr) {
                    int rb = r0 + fr * 16 + (lane >> 4) * 4;
#pragma unroll
                    for (int r = 0; r < 4; ++r)
                        out[(size_t)(rb + r) * 256 + d] = f2bf(fmaxf(acc[fr][fc][r] + bv, 0.f));
                }
            }
        }
        __threadfence();
        grid.sync();
        hin = out;
    }
}

// ---------------------------------------------------------------------------
// convT A-matrix build: a[m][c] = h0 + h6 (+ h6[parent]), bf16.  ONE launch.
// ---------------------------------------------------------------------------
__global__ __launch_bounds__(256)
void a_build(const unsigned short* __restrict__ h0, const unsigned short* __restrict__ h6,
             unsigned short* __restrict__ Ao)
{
    int bx = blockIdx.x;
    int P, H2, noff, pbase, pw, haspar; size_t aoff;
    if (bx < 1600)      { P = 1600; H2 = 40; noff = 0;    pbase = 1600; pw = 20; haspar = 1; aoff = 0; }
    else if (bx < 2000) { P = 400;  H2 = 20; noff = 1600; pbase = 2000; pw = 10; haspar = 1; aoff = 12800ULL * 256; bx -= 1600; }
    else                { P = 100;  H2 = 10; noff = 2000; pbase = 0;    pw = 0;  haspar = 0; aoff = 16000ULL * 256; bx -= 2000; }
    const int gid = bx * 256 + threadIdx.x;
    const int m = gid >> 5, c0 = (gid & 31) << 3;
    const int b = m / P, pix = m - b * P;
    const size_t src = ((size_t)(b * NODES + noff + pix)) * 256 + c0;
    u16x8 x0 = *(const u16x8*)(h0 + src);
    u16x8 x6 = *(const u16x8*)(h6 + src);
    float v[8];
#pragma unroll
    for (int e = 0; e < 8; ++e) v[e] = bf2f(x0[e]) + bf2f(x6[e]);
    if (haspar) {
        int ii = pix / H2, jj = pix - ii * H2;
        size_t sp = ((size_t)(b * NODES + pbase + (ii >> 1) * pw + (jj >> 1))) * 256 + c0;
        u16x8 xp = *(const u16x8*)(h6 + sp);
#pragma unroll
        for (int e = 0; e < 8; ++e) v[e] += bf2f(xp[e]);
    }
    u16x8 r;
#pragma unroll
    for (int e = 0; e < 8; ++e) r[e] = f2bf(v[e]);
    *(u16x8*)(Ao + aoff + (size_t)m * 256 + c0) = r;
}

// ---------------------------------------------------------------------------
// convT2x2 (+ feat0 copy on 512 dedicated blocks), role-swapped, all scales.
// ---------------------------------------------------------------------------
struct ConvtArgs {
    const unsigned short* WT[3];
    const unsigned short* Apix[3];
    const float* tb[3];
    const float* feat[3];
    float* out[3];
    const float4* cps; float4* cpd;
};

__global__ __launch_bounds__(256)
void convt_fused(ConvtArgs ct)
{
    __shared__ __align__(16) unsigned short As[8192], Bs[8192];
    int bx = blockIdx.x;
    if (bx < 512) { copy_chunk(ct.cps, ct.cpd, 13107200, bx, 512); return; }
    bx -= 512;
    int s, px, my;
    if (bx < 1600)      { s = 0; px = bx % 100; my = bx / 100; }
    else if (bx < 2400) { s = 1; bx -= 1600; px = bx % 25; my = bx / 25; }
    else                { s = 2; bx -= 2400; px = bx % 7;  my = bx / 7; }
    const int Pc[3]  = {1600, 400, 100};
    const int H2c[3] = {40, 20, 10};
    const int Cc[3]  = {512, 1024, 2048};
    const int Mc[3]  = {12800, 3200, 800};
    const int P = Pc[s], H2 = H2c[s], Cout = Cc[s], Mpix = Mc[s];
    const int m0 = my << 7, n0 = px << 7;

    f32x4 acc[4][4];
#pragma unroll
    for (int fr = 0; fr < 4; ++fr)
#pragma unroll
        for (int fc = 0; fc < 4; ++fc) acc[fr][fc] = (f32x4){0.f, 0.f, 0.f, 0.f};

    gemm_core(ct.WT[s], ct.Apix[s], 256, m0, n0, Cout * 4 - 1, Mpix - 1, As, Bs, acc);

    const int lane = threadIdx.x & 63, w = threadIdx.x >> 6;
    const int wr = w >> 1, wc = w & 1;
    const int H = H2 * 2;
    const float* feat = ct.feat[s];
    float* out = ct.out[s];
#pragma unroll
    for (int fc = 0; fc < 4; ++fc) {
        const int p_g = n0 + wc * 64 + fc * 16 + (lane & 15);
        if (p_g < Mpix) {
            const int b = p_g / P, pix = p_g - b * P;
            const int ii = pix / H2, jj = pix - ii * H2;
#pragma unroll
            for (int fr = 0; fr < 4; ++fr) {
                const int rb = m0 + wr * 64 + fr * 16 + (lane >> 4) * 4;
                const int o = rb >> 2;
                const float tbo = ct.tb[s][o];
                size_t base = (((size_t)(b * Cout + o)) * H + 2 * ii) * H + 2 * jj;
                float2 f0 = *(const float2*)&feat[base];
                float2 r0v; r0v.x = acc[fr][fc][0] + tbo + f0.x; r0v.y = acc[fr][fc][1] + tbo + f0.y;
                *(float2*)&out[base] = r0v;
                float2 f1 = *(const float2*)&feat[base + H];
                float2 r1v; r1v.x = acc[fr][fc][2] + tbo + f1.x; r1v.y = acc[fr][fc][3] + tbo + f1.y;
                *(float2*)&out[base + H] = r1v;
            }
        }
    }
}

// ---------------------------------------------------------------------------
extern "C" void kernel_launch(void* const* d_in, const int* in_sizes, int n_in,
                              void* d_out, int out_size, void* d_ws, size_t ws_size,
                              hipStream_t stream)
{
    const float* feats[3] = { (const float*)d_in[1], (const float*)d_in[2], (const float*)d_in[3] };
    const float* tb[3] = { (const float*)d_in[35], (const float*)d_in[37], (const float*)d_in[39] };

    // ---- workspace layout ----
    size_t off = 0;
    auto alloc = [&](size_t bytes) { size_t r = off; off = (off + bytes + 511) & ~(size_t)511; return r; };
    unsigned short* h0b  = (unsigned short*)((char*)d_ws + alloc(16800ULL * 256 * 2));
    unsigned short* hA   = (unsigned short*)((char*)d_ws + alloc(16800ULL * 256 * 2));
    unsigned short* hB   = (unsigned short*)((char*)d_ws + alloc(16800ULL * 256 * 2));
    unsigned short* dwb  = (unsigned short*)((char*)d_ws + alloc(917504ULL * 2));
    unsigned short* gWTb = (unsigned short*)((char*)d_ws + alloc(6ULL * 65536 * 2));
    unsigned short* tWTb = (unsigned short*)((char*)d_ws + alloc(3670016ULL * 2));
    float*          scshb= (float*)((char*)d_ws + alloc(3ULL * 512 * 4));
    unsigned short* Aconvt = (unsigned short*)((char*)d_ws + off);   // 8.6 MB

    // ---- mega-prep ----
    PrepArgs pa;
    pa.dw0 = (const float*)d_in[4];  pa.dw1 = (const float*)d_in[10]; pa.dw2 = (const float*)d_in[16];
    pa.gw0 = (const float*)d_in[22]; pa.gw1 = (const float*)d_in[24]; pa.gw2 = (const float*)d_in[26];
    pa.gw3 = (const float*)d_in[28]; pa.gw4 = (const float*)d_in[30]; pa.gw5 = (const float*)d_in[32];
    pa.tw0 = (const float*)d_in[34]; pa.tw1 = (const float*)d_in[36]; pa.tw2 = (const float*)d_in[38];
    pa.g0 = (const float*)d_in[6];  pa.g1 = (const float*)d_in[12]; pa.g2 = (const float*)d_in[18];
    pa.b0 = (const float*)d_in[7];  pa.b1 = (const float*)d_in[13]; pa.b2 = (const float*)d_in[19];
    pa.m0 = (const float*)d_in[8];  pa.m1 = (const float*)d_in[14]; pa.m2 = (const float*)d_in[20];
    pa.v0 = (const float*)d_in[9];  pa.v1 = (const float*)d_in[15]; pa.v2 = (const float*)d_in[21];
    pa.db0 = (const float*)d_in[5]; pa.db1 = (const float*)d_in[11]; pa.db2 = (const float*)d_in[17];
    pa.dwb = dwb; pa.gWTb = gWTb; pa.tWTb = tWTb; pa.scshb = scshb;
    mega_prep<<<dim3(4417), dim3(256), 0, stream>>>(pa);

    // ---- fused conv1x1 ----
    ConvArgs ca;
    ca.feat[0] = feats[0]; ca.feat[1] = feats[1]; ca.feat[2] = feats[2];
    ca.dwb[0] = dwb; ca.dwb[1] = dwb + 131072; ca.dwb[2] = dwb + 393216;
    ca.scsh[0] = scshb; ca.scsh[1] = scshb + 512; ca.scsh[2] = scshb + 1024;
    ca.h0out = h0b;
    conv_fused<<<dim3(1050), dim3(256), 0, stream>>>(ca);

    // ---- all 6 GNN layers, one cooperative kernel ----
    GnnAllArgs ga;
    ga.h0 = h0b; ga.bufA = hA; ga.bufB = hB; ga.WT = gWTb;
    ga.gb0 = (const float*)d_in[23]; ga.gb1 = (const float*)d_in[25];
    ga.gb2 = (const float*)d_in[27]; ga.gb3 = (const float*)d_in[29];
    ga.gb4 = (const float*)d_in[31]; ga.gb5 = (const float*)d_in[33];
    void* kargs[] = { (void*)&ga };
    hipLaunchCooperativeKernel(reinterpret_cast<void*>(gnn_all),
                               dim3(512), dim3(256), kargs, 0, stream);
    unsigned short* h6 = hB;   // layer 5 (odd) wrote bufB

    // ---- convT phase ----
    a_build<<<dim3(2100), dim3(256), 0, stream>>>(h0b, h6, Aconvt);

    ConvtArgs ct;
    ct.WT[0] = tWTb; ct.WT[1] = tWTb + 524288; ct.WT[2] = tWTb + 1572864;
    ct.Apix[0] = Aconvt; ct.Apix[1] = Aconvt + 12800ULL * 256; ct.Apix[2] = Aconvt + 16000ULL * 256;
    ct.tb[0] = tb[0]; ct.tb[1] = tb[1]; ct.tb[2] = tb[2];
    ct.feat[0] = feats[0]; ct.feat[1] = feats[1]; ct.feat[2] = feats[2];
    ct.out[0] = (float*)d_out + 52428800;
    ct.out[1] = (float*)d_out + 52428800 + 26214400;
    ct.out[2] = (float*)d_out + 52428800 + 26214400 + 13107200;
    ct.cps = (const float4*)d_in[0];
    ct.cpd = (float4*)d_out;
    convt_fused<<<dim3(512 + 2848), dim3(256), 0, stream>>>(ct);
}

// Round 7
// 488.470 us; speedup vs baseline: 2.4301x; 2.4301x over previous
//
#include <hip/hip_runtime.h>
#include <cstdint>

#define NODES 2100

typedef __attribute__((ext_vector_type(8))) __bf16 bf16x8;
typedef __attribute__((ext_vector_type(4))) float f32x4;
typedef __attribute__((ext_vector_type(8))) unsigned short u16x8;

__device__ inline float bf2f(unsigned short s) { return __uint_as_float(((unsigned)s) << 16); }
__device__ inline unsigned short f2bf(float f) {
    unsigned u = __float_as_uint(f);
    u += 0x7fff + ((u >> 16) & 1);          // RNE
    return (unsigned short)(u >> 16);
}
__device__ inline void gload16(const unsigned short* g, void* lds) {
    __builtin_amdgcn_global_load_lds(
        (const __attribute__((address_space(1))) void*)g,
        (__attribute__((address_space(3))) void*)lds, 16, 0, 0);
}

// grid-strided float4 copy over the first `nb` blocks of a launch
__device__ inline void copy_chunk(const float4* __restrict__ s, float4* __restrict__ d,
                                  int nquads, int bid, int nb)
{
    for (int i = bid * 256 + threadIdx.x; i < nquads; i += nb * 256) d[i] = s[i];
}

// ---------------------------------------------------------------------------
// Shared MFMA GEMM core (convt), 128x128 tile, BK=64, XOR-swizzled LDS
// both sides (linear dest + pre-swizzled source + swizzled read).
// ---------------------------------------------------------------------------
__device__ __attribute__((always_inline)) inline
void gemm_core(const unsigned short* __restrict__ A, const unsigned short* __restrict__ B,
               int K, int m0, int n0, int mClamp, int nClamp,
               unsigned short* As, unsigned short* Bs, f32x4 acc[4][4])
{
    const int t = threadIdx.x, lane = t & 63, w = t >> 6;
    const int wr = w >> 1, wc = w & 1;
    const int sx = (lane & 7) << 4;
    for (int k0 = 0; k0 < K; k0 += 64) {
#pragma unroll
        for (int i = 0; i < 4; ++i) {
            int LO  = ((i << 8) + t) << 4;
            int row = LO >> 7;
            int kb  = (LO & 127) ^ ((row & 7) << 4);
            int ke  = kb >> 1;
            int ra = m0 + row; if (ra > mClamp) ra = mClamp;
            int rb = n0 + row; if (rb > nClamp) rb = nClamp;
            gload16(A + (size_t)ra * K + k0 + ke, (char*)As + LO);
            gload16(B + (size_t)rb * K + k0 + ke, (char*)Bs + LO);
        }
        asm volatile("s_waitcnt vmcnt(0)" ::: "memory");
        __syncthreads();
#pragma unroll
        for (int kk = 0; kk < 2; ++kk) {
            bf16x8 a[4], bb[4];
#pragma unroll
            for (int f = 0; f < 4; ++f) {
                int pa = (((wr * 64 + f * 16 + (lane & 15)) << 7) + kk * 64 + ((lane >> 4) << 4)) ^ sx;
                int pb = (((wc * 64 + f * 16 + (lane & 15)) << 7) + kk * 64 + ((lane >> 4) << 4)) ^ sx;
                a[f]  = *(const bf16x8*)((const char*)As + pa);
                bb[f] = *(const bf16x8*)((const char*)Bs + pb);
            }
#pragma unroll
            for (int fr = 0; fr < 4; ++fr)
#pragma unroll
                for (int fc = 0; fc < 4; ++fc)
                    acc[fr][fc] = __builtin_amdgcn_mfma_f32_16x16x32_bf16(a[fr], bb[fc], acc[fr][fc], 0, 0, 0);
        }
        __syncthreads();
    }
}

// ---------------------------------------------------------------------------
// mega-prep: weight conversions/transposes + BN scale/shift, one launch
// ---------------------------------------------------------------------------
struct PrepArgs {
    const float *dw0, *dw1, *dw2;
    const float *gw0, *gw1, *gw2, *gw3, *gw4, *gw5;
    const float *tw0, *tw1, *tw2;
    const float *g0, *g1, *g2, *b0, *b1, *b2, *m0, *m1, *m2, *v0, *v1, *v2, *db0, *db1, *db2;
    unsigned short *dwb, *gWTb, *tWTb;
    float *scshb;
};

__device__ inline void transpose32(const float* __restrict__ in, unsigned short* __restrict__ outT,
                                   int Ccols, int c0, int r0)
{
    __shared__ float T[32][33];
    const int tx = threadIdx.x & 31, ty = threadIdx.x >> 5;
#pragma unroll
    for (int i = 0; i < 4; ++i)
        T[ty + i * 8][tx] = in[(size_t)(r0 + ty + i * 8) * Ccols + c0 + tx];
    __syncthreads();
#pragma unroll
    for (int i = 0; i < 4; ++i)
        outT[(size_t)(c0 + ty + i * 8) * 256 + r0 + tx] = f2bf(T[tx][ty + i * 8]);
}

__global__ __launch_bounds__(256)
void mega_prep(PrepArgs a)
{
    int bid = blockIdx.x;
    const int t = threadIdx.x;
    if (bid < 448) {                           // dw convert (concatenated)
        int idx = (bid * 256 + t) * 8;
        const float* src;
        int loc;
        if (idx < 131072)      { src = a.dw0; loc = idx; }
        else if (idx < 393216) { src = a.dw1; loc = idx - 131072; }
        else                   { src = a.dw2; loc = idx - 393216; }
        float4 x = *(const float4*)(src + loc);
        float4 y = *(const float4*)(src + loc + 4);
        u16x8 r;
        r[0] = f2bf(x.x); r[1] = f2bf(x.y); r[2] = f2bf(x.z); r[3] = f2bf(x.w);
        r[4] = f2bf(y.x); r[5] = f2bf(y.y); r[6] = f2bf(y.z); r[7] = f2bf(y.w);
        *(u16x8*)(a.dwb + idx) = r;
    } else if (bid < 832) {                    // gW transpose: 6 x (8x8 blocks)
        int gid = bid - 448;
        int l = gid >> 6, sb = gid & 63;
        const float* gw[6] = {a.gw0, a.gw1, a.gw2, a.gw3, a.gw4, a.gw5};
        transpose32(gw[l], a.gWTb + (size_t)l * 65536, 256, (sb & 7) << 5, (sb >> 3) << 5);
    } else if (bid < 4416) {                   // tW transpose
        int gid = bid - 832;
        const float* tw; unsigned short* dst; int ncx, loc;
        if (gid < 512)       { tw = a.tw0; dst = a.tWTb;           ncx = 64;  loc = gid; }
        else if (gid < 1536) { tw = a.tw1; dst = a.tWTb + 524288;  ncx = 128; loc = gid - 512; }
        else                 { tw = a.tw2; dst = a.tWTb + 1572864; ncx = 256; loc = gid - 1536; }
        int cx = loc % ncx, ry = loc / ncx;
        transpose32(tw, dst, ncx * 32, cx << 5, ry << 5);
    } else {                                   // BN scale/shift
        const float* g[3]  = {a.g0, a.g1, a.g2};
        const float* b[3]  = {a.b0, a.b1, a.b2};
        const float* m[3]  = {a.m0, a.m1, a.m2};
        const float* v[3]  = {a.v0, a.v1, a.v2};
        const float* db[3] = {a.db0, a.db1, a.db2};
        for (int s = 0; s < 3; ++s) {
            float sc = g[s][t] * rsqrtf(v[s][t] + 1e-5f);
            a.scshb[s * 512 + t] = sc;
            a.scshb[s * 512 + 256 + t] = (db[s][t] - m[s][t]) * sc + b[s][t];
        }
    }
}

// ---------------------------------------------------------------------------
// Fused conv1x1: transpose-stage fp32 feat into swizzled LDS, MFMA vs
// weights (BM=64 x BN=256, all scales, one launch), BN+ReLU+pool epilogue.
// ---------------------------------------------------------------------------
struct ConvArgs {
    const float* feat[3];
    const unsigned short* dwb[3];
    const float* scsh[3];
    unsigned short* h0out;
};

__global__ __launch_bounds__(256)
void conv_fused(ConvArgs ca)
{
    __shared__ __align__(16) unsigned short As[64 * 64];   // swizzled, 8 KB
    __shared__ __align__(16) unsigned short Bs[256 * 64];  // swizzled, 32 KB
    int bx = blockIdx.x;
    int s, mt;
    if (bx < 800)       { s = 0; mt = bx; }
    else if (bx < 1000) { s = 1; mt = bx - 800; }
    else                { s = 2; mt = bx - 1000; }
    const int Kc[3]  = {512, 1024, 2048};
    const int Wc[3]  = {80, 40, 20};
    const int PPc[3] = {1600, 400, 100};
    const int nfc[3] = {0, 1600, 2000};
    const int K = Kc[s], W = Wc[s], W2 = W >> 1, HW = W * W, PP = PPc[s], noff = nfc[s];
    const float* feat = ca.feat[s];
    const unsigned short* dw = ca.dwb[s];
    const float* scsh = ca.scsh[s];

    const int t = threadIdx.x, lane = t & 63, w = t >> 6;
    const int sx = (lane & 7) << 4;

    const int ml = t & 63;
    const int kw = t >> 6;
    const int graw = mt * 64 + ml;
    const int b = graw / HW;
    const int rem = graw - b * HW;
    const int pooled = rem >> 2, sub = rem & 3;
    const int pi = pooled / W2, pj = pooled - pi * W2;
    const int i = pi * 2 + (sub >> 1), j = pj * 2 + (sub & 1);
    const float* src = feat + (size_t)b * K * HW + (size_t)i * W + j;
    const int sxm = (ml & 7) << 3;

    f32x4 acc[4][4];
#pragma unroll
    for (int fr = 0; fr < 4; ++fr)
#pragma unroll
        for (int fc = 0; fc < 4; ++fc) acc[fr][fc] = (f32x4){0.f, 0.f, 0.f, 0.f};

    for (int k0 = 0; k0 < K; k0 += 64) {
#pragma unroll
        for (int it = 0; it < 8; ++it) {
            int LO = ((it << 8) + t) << 4;
            int row = LO >> 7;
            int kb = (LO & 127) ^ ((row & 7) << 4);
            gload16(dw + (size_t)row * K + k0 + (kb >> 1), (char*)Bs + LO);
        }
        float v[16];
#pragma unroll
        for (int it = 0; it < 16; ++it)
            v[it] = src[(size_t)(k0 + it * 4 + kw) * HW];
#pragma unroll
        for (int it = 0; it < 16; ++it) {
            int k_l = it * 4 + kw;
            As[(ml << 6) + (k_l ^ sxm)] = f2bf(v[it]);
        }
        asm volatile("s_waitcnt vmcnt(0)" ::: "memory");
        __syncthreads();
#pragma unroll
        for (int kk = 0; kk < 2; ++kk) {
            bf16x8 a[4], bb[4];
#pragma unroll
            for (int f = 0; f < 4; ++f) {
                int pa = (((f * 16 + (lane & 15)) << 7) + kk * 64 + ((lane >> 4) << 4)) ^ sx;
                int pb = (((w * 64 + f * 16 + (lane & 15)) << 7) + kk * 64 + ((lane >> 4) << 4)) ^ sx;
                a[f]  = *(const bf16x8*)((const char*)As + pa);
                bb[f] = *(const bf16x8*)((const char*)Bs + pb);
            }
#pragma unroll
            for (int fr = 0; fr < 4; ++fr)
#pragma unroll
                for (int fc = 0; fc < 4; ++fc)
                    acc[fr][fc] = __builtin_amdgcn_mfma_f32_16x16x32_bf16(a[fr], bb[fc], acc[fr][fc], 0, 0, 0);
        }
        __syncthreads();
    }

#pragma unroll
    for (int fc = 0; fc < 4; ++fc) {
        const int o = w * 64 + fc * 16 + (lane & 15);
        const float sc = scsh[o], sh = scsh[256 + o];
#pragma unroll
        for (int fr = 0; fr < 4; ++fr) {
            const int mrow = mt * 64 + fr * 16 + (lane >> 4) * 4;
            const int q = mrow >> 2;
            const int bi = q / PP;
            const int node = noff + (q - bi * PP);
            float sum = 0.f;
#pragma unroll
            for (int r = 0; r < 4; ++r)
                sum += fmaxf(acc[fr][fc][r] * sc + sh, 0.f);
            ca.h0out[((size_t)(bi * NODES + node)) * 256 + o] = f2bf(sum * 0.25f);
        }
    }
}

// ---------------------------------------------------------------------------
// Fused GNN layer, BM=32 (525 blocks), gather software-pipelined:
// next k-step's 9 neighbor loads issued during the MFMA phase.
// ---------------------------------------------------------------------------
__global__ __launch_bounds__(256)
void gnn_fused(const unsigned short* __restrict__ h, const unsigned short* __restrict__ BT,
               const float* __restrict__ bias, unsigned short* __restrict__ out, int hier)
{
    __shared__ __align__(16) unsigned short As[32 * 64];   // swizzled, 4 KB
    __shared__ __align__(16) unsigned short Bs[256 * 64];  // swizzled, 32 KB
    const int t = threadIdx.x, lane = t & 63, w = t >> 6;
    const int r0 = blockIdx.x << 5;
    const int myrow = t >> 3, q = t & 7;      // 8 threads per row, 8 k each
    const int grow = r0 + myrow;              // 16800 = 525*32
    const int b = grow / NODES;
    const int n = grow - b * NODES;

    int gw, off;
    if (n < 1600)      { gw = 40; off = 0; }
    else if (n < 2000) { gw = 20; off = 1600; }
    else               { gw = 10; off = 2000; }
    const int li = (n - off) / gw;
    const int lj = (n - off) - li * gw;
    int nbr[9]; int cnt = 0;
    if (!hier) {
#pragma unroll
        for (int di = -1; di <= 1; ++di)
#pragma unroll
            for (int dj = -1; dj <= 1; ++dj) {
                int ii = li + di, jj = lj + dj;
                if (ii >= 0 && ii < gw && jj >= 0 && jj < gw) nbr[cnt++] = off + ii * gw + jj;
            }
    } else {
        nbr[cnt++] = n;
        if (off == 0) {
            nbr[cnt++] = 1600 + (li >> 1) * 20 + (lj >> 1);
        } else if (off == 1600) {
            nbr[cnt++] = 2000 + (li >> 1) * 10 + (lj >> 1);
#pragma unroll
            for (int di = 0; di < 2; ++di)
#pragma unroll
                for (int dj = 0; dj < 2; ++dj)
                    nbr[cnt++] = ((li << 1) + di) * 40 + ((lj << 1) + dj);
        } else {
#pragma unroll
            for (int di = 0; di < 2; ++di)
#pragma unroll
                for (int dj = 0; dj < 2; ++dj)
                    nbr[cnt++] = 1600 + ((li << 1) + di) * 20 + ((lj << 1) + dj);
        }
    }
    int nboff[9];
#pragma unroll
    for (int e = 0; e < 9; ++e)
        nboff[e] = (b * NODES + nbr[e < cnt ? e : 0]) * 256 + q * 8;
    const float inv = 1.0f / (float)cnt;
    const int sx = (lane & 7) << 4;
    const int awr = (myrow << 6) + ((q ^ (myrow & 7)) << 3);  // swizzled write slot

    f32x4 acc[2][4];
#pragma unroll
    for (int fr = 0; fr < 2; ++fr)
#pragma unroll
        for (int fc = 0; fc < 4; ++fc) acc[fr][fc] = (f32x4){0.f, 0.f, 0.f, 0.f};

    // prefetch gather for k0 = 0
    u16x8 pre[9];
#pragma unroll
    for (int e = 0; e < 9; ++e) pre[e] = *(const u16x8*)(h + nboff[e]);

    for (int k0 = 0; k0 < 256; k0 += 64) {
        // B stage (weights, swizzled source)
#pragma unroll
        for (int it = 0; it < 8; ++it) {
            int LO = ((it << 8) + t) << 4;
            int row = LO >> 7;
            int kb = (LO & 127) ^ ((row & 7) << 4);
            gload16(BT + (size_t)row * 256 + k0 + (kb >> 1), (char*)Bs + LO);
        }
        // accumulate current prefetched gather (static indexing, predicated)
        float sacc[8] = {0, 0, 0, 0, 0, 0, 0, 0};
#pragma unroll
        for (int e = 0; e < 9; ++e) {
            if (e < cnt) {
#pragma unroll
                for (int jj = 0; jj < 8; ++jj) sacc[jj] += bf2f(pre[e][jj]);
            }
        }
        u16x8 o0;
#pragma unroll
        for (int jj = 0; jj < 8; ++jj) o0[jj] = f2bf(sacc[jj] * inv);
        *(u16x8*)&As[awr] = o0;

        asm volatile("s_waitcnt vmcnt(0)" ::: "memory");   // drains B-stage glds only
        __syncthreads();

        // prefetch next k-step's gather; in flight during MFMA
        const int k0n = (k0 + 64) & 255;
#pragma unroll
        for (int e = 0; e < 9; ++e) pre[e] = *(const u16x8*)(h + nboff[e] + k0n);

#pragma unroll
        for (int kk = 0; kk < 2; ++kk) {
            bf16x8 a[2], bb[4];
#pragma unroll
            for (int f = 0; f < 2; ++f) {
                int pa = (((f * 16 + (lane & 15)) << 7) + kk * 64 + ((lane >> 4) << 4)) ^ sx;
                a[f] = *(const bf16x8*)((const char*)As + pa);
            }
#pragma unroll
            for (int f = 0; f < 4; ++f) {
                int pb = (((w * 64 + f * 16 + (lane & 15)) << 7) + kk * 64 + ((lane >> 4) << 4)) ^ sx;
                bb[f] = *(const bf16x8*)((const char*)Bs + pb);
            }
#pragma unroll
            for (int fr = 0; fr < 2; ++fr)
#pragma unroll
                for (int fc = 0; fc < 4; ++fc)
                    acc[fr][fc] = __builtin_amdgcn_mfma_f32_16x16x32_bf16(a[fr], bb[fc], acc[fr][fc], 0, 0, 0);
        }
        __syncthreads();
    }

#pragma unroll
    for (int fc = 0; fc < 4; ++fc) {
        const int d = w * 64 + fc * 16 + (lane & 15);
        const float bv = bias[d];
#pragma unroll
        for (int fr = 0; fr < 2; ++fr) {
            int rb = r0 + fr * 16 + (lane >> 4) * 4;
#pragma unroll
            for (int r = 0; r < 4; ++r)
                out[(size_t)(rb + r) * 256 + d] = f2bf(fmaxf(acc[fr][fc][r] + bv, 0.f));
        }
    }
}

// ---------------------------------------------------------------------------
// convT A-matrix build: a[m][c] = h0 + h6 (+ h6[parent]), bf16.  ONE launch.
// ---------------------------------------------------------------------------
__global__ __launch_bounds__(256)
void a_build(const unsigned short* __restrict__ h0, const unsigned short* __restrict__ h6,
             unsigned short* __restrict__ Ao)
{
    int bx = blockIdx.x;
    int P, H2, noff, pbase, pw, haspar; size_t aoff;
    if (bx < 1600)      { P = 1600; H2 = 40; noff = 0;    pbase = 1600; pw = 20; haspar = 1; aoff = 0; }
    else if (bx < 2000) { P = 400;  H2 = 20; noff = 1600; pbase = 2000; pw = 10; haspar = 1; aoff = 12800ULL * 256; bx -= 1600; }
    else                { P = 100;  H2 = 10; noff = 2000; pbase = 0;    pw = 0;  haspar = 0; aoff = 16000ULL * 256; bx -= 2000; }
    const int gid = bx * 256 + threadIdx.x;
    const int m = gid >> 5, c0 = (gid & 31) << 3;
    const int b = m / P, pix = m - b * P;
    const size_t src = ((size_t)(b * NODES + noff + pix)) * 256 + c0;
    u16x8 x0 = *(const u16x8*)(h0 + src);
    u16x8 x6 = *(const u16x8*)(h6 + src);
    float v[8];
#pragma unroll
    for (int e = 0; e < 8; ++e) v[e] = bf2f(x0[e]) + bf2f(x6[e]);
    if (haspar) {
        int ii = pix / H2, jj = pix - ii * H2;
        size_t sp = ((size_t)(b * NODES + pbase + (ii >> 1) * pw + (jj >> 1))) * 256 + c0;
        u16x8 xp = *(const u16x8*)(h6 + sp);
#pragma unroll
        for (int e = 0; e < 8; ++e) v[e] += bf2f(xp[e]);
    }
    u16x8 r;
#pragma unroll
    for (int e = 0; e < 8; ++e) r[e] = f2bf(v[e]);
    *(u16x8*)(Ao + aoff + (size_t)m * 256 + c0) = r;
}

// ---------------------------------------------------------------------------
// convT2x2 (+ feat0 copy on 512 dedicated blocks), role-swapped, all scales.
// ---------------------------------------------------------------------------
struct ConvtArgs {
    const unsigned short* WT[3];
    const unsigned short* Apix[3];
    const float* tb[3];
    const float* feat[3];
    float* out[3];
    const float4* cps; float4* cpd;
};

__global__ __launch_bounds__(256)
void convt_fused(ConvtArgs ct)
{
    __shared__ __align__(16) unsigned short As[8192], Bs[8192];
    int bx = blockIdx.x;
    if (bx < 512) { copy_chunk(ct.cps, ct.cpd, 13107200, bx, 512); return; }
    bx -= 512;
    int s, px, my;
    if (bx < 1600)      { s = 0; px = bx % 100; my = bx / 100; }
    else if (bx < 2400) { s = 1; bx -= 1600; px = bx % 25; my = bx / 25; }
    else                { s = 2; bx -= 2400; px = bx % 7;  my = bx / 7; }
    const int Pc[3]  = {1600, 400, 100};
    const int H2c[3] = {40, 20, 10};
    const int Cc[3]  = {512, 1024, 2048};
    const int Mc[3]  = {12800, 3200, 800};
    const int P = Pc[s], H2 = H2c[s], Cout = Cc[s], Mpix = Mc[s];
    const int m0 = my << 7, n0 = px << 7;

    f32x4 acc[4][4];
#pragma unroll
    for (int fr = 0; fr < 4; ++fr)
#pragma unroll
        for (int fc = 0; fc < 4; ++fc) acc[fr][fc] = (f32x4){0.f, 0.f, 0.f, 0.f};

    gemm_core(ct.WT[s], ct.Apix[s], 256, m0, n0, Cout * 4 - 1, Mpix - 1, As, Bs, acc);

    const int lane = threadIdx.x & 63, w = threadIdx.x >> 6;
    const int wr = w >> 1, wc = w & 1;
    const int H = H2 * 2;
    const float* feat = ct.feat[s];
    float* out = ct.out[s];
#pragma unroll
    for (int fc = 0; fc < 4; ++fc) {
        const int p_g = n0 + wc * 64 + fc * 16 + (lane & 15);
        if (p_g < Mpix) {
            const int b = p_g / P, pix = p_g - b * P;
            const int ii = pix / H2, jj = pix - ii * H2;
#pragma unroll
            for (int fr = 0; fr < 4; ++fr) {
                const int rb = m0 + wr * 64 + fr * 16 + (lane >> 4) * 4;
                const int o = rb >> 2;
                const float tbo = ct.tb[s][o];
                size_t base = (((size_t)(b * Cout + o)) * H + 2 * ii) * H + 2 * jj;
                float2 f0 = *(const float2*)&feat[base];
                float2 r0v; r0v.x = acc[fr][fc][0] + tbo + f0.x; r0v.y = acc[fr][fc][1] + tbo + f0.y;
                *(float2*)&out[base] = r0v;
                float2 f1 = *(const float2*)&feat[base + H];
                float2 r1v; r1v.x = acc[fr][fc][2] + tbo + f1.x; r1v.y = acc[fr][fc][3] + tbo + f1.y;
                *(float2*)&out[base + H] = r1v;
            }
        }
    }
}

// ---------------------------------------------------------------------------
extern "C" void kernel_launch(void* const* d_in, const int* in_sizes, int n_in,
                              void* d_out, int out_size, void* d_ws, size_t ws_size,
                              hipStream_t stream)
{
    const float* feats[3] = { (const float*)d_in[1], (const float*)d_in[2], (const float*)d_in[3] };
    const float* gb[6];
    for (int l = 0; l < 6; ++l) gb[l] = (const float*)d_in[23 + 2 * l];
    const float* tb[3] = { (const float*)d_in[35], (const float*)d_in[37], (const float*)d_in[39] };

    // ---- workspace layout ----
    size_t off = 0;
    auto alloc = [&](size_t bytes) { size_t r = off; off = (off + bytes + 511) & ~(size_t)511; return r; };
    unsigned short* h0b  = (unsigned short*)((char*)d_ws + alloc(16800ULL * 256 * 2));
    unsigned short* hA   = (unsigned short*)((char*)d_ws + alloc(16800ULL * 256 * 2));
    unsigned short* hB   = (unsigned short*)((char*)d_ws + alloc(16800ULL * 256 * 2));
    unsigned short* dwb  = (unsigned short*)((char*)d_ws + alloc(917504ULL * 2));
    unsigned short* gWTb = (unsigned short*)((char*)d_ws + alloc(6ULL * 65536 * 2));
    unsigned short* tWTb = (unsigned short*)((char*)d_ws + alloc(3670016ULL * 2));
    float*          scshb= (float*)((char*)d_ws + alloc(3ULL * 512 * 4));
    unsigned short* Aconvt = (unsigned short*)((char*)d_ws + off);   // 8.6 MB

    // ---- mega-prep ----
    PrepArgs pa;
    pa.dw0 = (const float*)d_in[4];  pa.dw1 = (const float*)d_in[10]; pa.dw2 = (const float*)d_in[16];
    pa.gw0 = (const float*)d_in[22]; pa.gw1 = (const float*)d_in[24]; pa.gw2 = (const float*)d_in[26];
    pa.gw3 = (const float*)d_in[28]; pa.gw4 = (const float*)d_in[30]; pa.gw5 = (const float*)d_in[32];
    pa.tw0 = (const float*)d_in[34]; pa.tw1 = (const float*)d_in[36]; pa.tw2 = (const float*)d_in[38];
    pa.g0 = (const float*)d_in[6];  pa.g1 = (const float*)d_in[12]; pa.g2 = (const float*)d_in[18];
    pa.b0 = (const float*)d_in[7];  pa.b1 = (const float*)d_in[13]; pa.b2 = (const float*)d_in[19];
    pa.m0 = (const float*)d_in[8];  pa.m1 = (const float*)d_in[14]; pa.m2 = (const float*)d_in[20];
    pa.v0 = (const float*)d_in[9];  pa.v1 = (const float*)d_in[15]; pa.v2 = (const float*)d_in[21];
    pa.db0 = (const float*)d_in[5]; pa.db1 = (const float*)d_in[11]; pa.db2 = (const float*)d_in[17];
    pa.dwb = dwb; pa.gWTb = gWTb; pa.tWTb = tWTb; pa.scshb = scshb;
    mega_prep<<<dim3(4417), dim3(256), 0, stream>>>(pa);

    // ---- fused conv1x1 ----
    ConvArgs ca;
    ca.feat[0] = feats[0]; ca.feat[1] = feats[1]; ca.feat[2] = feats[2];
    ca.dwb[0] = dwb; ca.dwb[1] = dwb + 131072; ca.dwb[2] = dwb + 393216;
    ca.scsh[0] = scshb; ca.scsh[1] = scshb + 512; ca.scsh[2] = scshb + 1024;
    ca.h0out = h0b;
    conv_fused<<<dim3(1050), dim3(256), 0, stream>>>(ca);

    // ---- 6 fused GNN layers ----
    const int types[6] = {0, 0, 1, 1, 0, 0};
    const unsigned short* hin = h0b;
    unsigned short* houts[6] = {hA, hB, hA, hB, hA, hB};
    for (int l = 0; l < 6; ++l) {
        gnn_fused<<<dim3(525), dim3(256), 0, stream>>>(
            hin, gWTb + (size_t)l * 65536, gb[l], houts[l], types[l]);
        hin = houts[l];
    }
    unsigned short* h6 = hB;

    // ---- convT phase ----
    a_build<<<dim3(2100), dim3(256), 0, stream>>>(h0b, h6, Aconvt);

    ConvtArgs ct;
    ct.WT[0] = tWTb; ct.WT[1] = tWTb + 524288; ct.WT[2] = tWTb + 1572864;
    ct.Apix[0] = Aconvt; ct.Apix[1] = Aconvt + 12800ULL * 256; ct.Apix[2] = Aconvt + 16000ULL * 256;
    ct.tb[0] = tb[0]; ct.tb[1] = tb[1]; ct.tb[2] = tb[2];
    ct.feat[0] = feats[0]; ct.feat[1] = feats[1]; ct.feat[2] = feats[2];
    ct.out[0] = (float*)d_out + 52428800;
    ct.out[1] = (float*)d_out + 52428800 + 26214400;
    ct.out[2] = (float*)d_out + 52428800 + 26214400 + 13107200;
    ct.cps = (const float4*)d_in[0];
    ct.cpd = (float4*)d_out;
    convt_fused<<<dim3(512 + 2848), dim3(256), 0, stream>>>(ct);
}

// Round 8
// 444.231 us; speedup vs baseline: 2.6721x; 1.0996x over previous
//
#include <hip/hip_runtime.h>
#include <cstdint>

#define NODES 2100

typedef __attribute__((ext_vector_type(8))) __bf16 bf16x8;
typedef __attribute__((ext_vector_type(4))) float f32x4;
typedef __attribute__((ext_vector_type(8))) unsigned short u16x8;

__device__ inline float bf2f(unsigned short s) { return __uint_as_float(((unsigned)s) << 16); }
__device__ inline unsigned short f2bf(float f) {
    unsigned u = __float_as_uint(f);
    u += 0x7fff + ((u >> 16) & 1);          // RNE
    return (unsigned short)(u >> 16);
}
__device__ inline void gload16(const unsigned short* g, void* lds) {
    __builtin_amdgcn_global_load_lds(
        (const __attribute__((address_space(1))) void*)g,
        (__attribute__((address_space(3))) void*)lds, 16, 0, 0);
}

// ---------------------------------------------------------------------------
// mega-prep: weight conversions/transposes + BN scale/shift, one launch
// ---------------------------------------------------------------------------
struct PrepArgs {
    const float *dw0, *dw1, *dw2;
    const float *gw0, *gw1, *gw2, *gw3, *gw4, *gw5;
    const float *tw0, *tw1, *tw2;
    const float *g0, *g1, *g2, *b0, *b1, *b2, *m0, *m1, *m2, *v0, *v1, *v2, *db0, *db1, *db2;
    unsigned short *dwb, *gWTb, *tWTb;
    float *scshb;
};

__device__ inline void transpose32(const float* __restrict__ in, unsigned short* __restrict__ outT,
                                   int Ccols, int c0, int r0)
{
    __shared__ float T[32][33];
    const int tx = threadIdx.x & 31, ty = threadIdx.x >> 5;
#pragma unroll
    for (int i = 0; i < 4; ++i)
        T[ty + i * 8][tx] = in[(size_t)(r0 + ty + i * 8) * Ccols + c0 + tx];
    __syncthreads();
#pragma unroll
    for (int i = 0; i < 4; ++i)
        outT[(size_t)(c0 + ty + i * 8) * 256 + r0 + tx] = f2bf(T[tx][ty + i * 8]);
}

__global__ __launch_bounds__(256)
void mega_prep(PrepArgs a)
{
    int bid = blockIdx.x;
    const int t = threadIdx.x;
    if (bid < 448) {                           // dw convert (concatenated)
        int idx = (bid * 256 + t) * 8;
        const float* src;
        int loc;
        if (idx < 131072)      { src = a.dw0; loc = idx; }
        else if (idx < 393216) { src = a.dw1; loc = idx - 131072; }
        else                   { src = a.dw2; loc = idx - 393216; }
        float4 x = *(const float4*)(src + loc);
        float4 y = *(const float4*)(src + loc + 4);
        u16x8 r;
        r[0] = f2bf(x.x); r[1] = f2bf(x.y); r[2] = f2bf(x.z); r[3] = f2bf(x.w);
        r[4] = f2bf(y.x); r[5] = f2bf(y.y); r[6] = f2bf(y.z); r[7] = f2bf(y.w);
        *(u16x8*)(a.dwb + idx) = r;
    } else if (bid < 832) {                    // gW transpose: 6 x (8x8 blocks)
        int gid = bid - 448;
        int l = gid >> 6, sb = gid & 63;
        const float* gw[6] = {a.gw0, a.gw1, a.gw2, a.gw3, a.gw4, a.gw5};
        transpose32(gw[l], a.gWTb + (size_t)l * 65536, 256, (sb & 7) << 5, (sb >> 3) << 5);
    } else if (bid < 4416) {                   // tW transpose
        int gid = bid - 832;
        const float* tw; unsigned short* dst; int ncx, loc;
        if (gid < 512)       { tw = a.tw0; dst = a.tWTb;           ncx = 64;  loc = gid; }
        else if (gid < 1536) { tw = a.tw1; dst = a.tWTb + 524288;  ncx = 128; loc = gid - 512; }
        else                 { tw = a.tw2; dst = a.tWTb + 1572864; ncx = 256; loc = gid - 1536; }
        int cx = loc % ncx, ry = loc / ncx;
        transpose32(tw, dst, ncx * 32, cx << 5, ry << 5);
    } else {                                   // BN scale/shift
        const float* g[3]  = {a.g0, a.g1, a.g2};
        const float* b[3]  = {a.b0, a.b1, a.b2};
        const float* m[3]  = {a.m0, a.m1, a.m2};
        const float* v[3]  = {a.v0, a.v1, a.v2};
        const float* db[3] = {a.db0, a.db1, a.db2};
        for (int s = 0; s < 3; ++s) {
            float sc = g[s][t] * rsqrtf(v[s][t] + 1e-5f);
            a.scshb[s * 512 + t] = sc;
            a.scshb[s * 512 + 256 + t] = (db[s][t] - m[s][t]) * sc + b[s][t];
        }
    }
}

// ---------------------------------------------------------------------------
// Fused conv1x1: transpose-stage fp32 feat into swizzled LDS, MFMA vs
// weights (BM=64 x BN=256, all scales, one launch), BN+ReLU+pool epilogue.
// ---------------------------------------------------------------------------
struct ConvArgs {
    const float* feat[3];
    const unsigned short* dwb[3];
    const float* scsh[3];
    unsigned short* h0out;
};

__global__ __launch_bounds__(256)
void conv_fused(ConvArgs ca)
{
    __shared__ __align__(16) unsigned short As[64 * 64];   // swizzled, 8 KB
    __shared__ __align__(16) unsigned short Bs[256 * 64];  // swizzled, 32 KB
    int bx = blockIdx.x;
    int s, mt;
    if (bx < 800)       { s = 0; mt = bx; }
    else if (bx < 1000) { s = 1; mt = bx - 800; }
    else                { s = 2; mt = bx - 1000; }
    const int Kc[3]  = {512, 1024, 2048};
    const int Wc[3]  = {80, 40, 20};
    const int PPc[3] = {1600, 400, 100};
    const int nfc[3] = {0, 1600, 2000};
    const int K = Kc[s], W = Wc[s], W2 = W >> 1, HW = W * W, PP = PPc[s], noff = nfc[s];
    const float* feat = ca.feat[s];
    const unsigned short* dw = ca.dwb[s];
    const float* scsh = ca.scsh[s];

    const int t = threadIdx.x, lane = t & 63, w = t >> 6;
    const int sx = (lane & 7) << 4;

    const int ml = t & 63;
    const int kw = t >> 6;
    const int graw = mt * 64 + ml;
    const int b = graw / HW;
    const int rem = graw - b * HW;
    const int pooled = rem >> 2, sub = rem & 3;
    const int pi = pooled / W2, pj = pooled - pi * W2;
    const int i = pi * 2 + (sub >> 1), j = pj * 2 + (sub & 1);
    const float* src = feat + (size_t)b * K * HW + (size_t)i * W + j;
    const int sxm = (ml & 7) << 3;

    f32x4 acc[4][4];
#pragma unroll
    for (int fr = 0; fr < 4; ++fr)
#pragma unroll
        for (int fc = 0; fc < 4; ++fc) acc[fr][fc] = (f32x4){0.f, 0.f, 0.f, 0.f};

    for (int k0 = 0; k0 < K; k0 += 64) {
#pragma unroll
        for (int it = 0; it < 8; ++it) {
            int LO = ((it << 8) + t) << 4;
            int row = LO >> 7;
            int kb = (LO & 127) ^ ((row & 7) << 4);
            gload16(dw + (size_t)row * K + k0 + (kb >> 1), (char*)Bs + LO);
        }
        float v[16];
#pragma unroll
        for (int it = 0; it < 16; ++it)
            v[it] = src[(size_t)(k0 + it * 4 + kw) * HW];
#pragma unroll
        for (int it = 0; it < 16; ++it) {
            int k_l = it * 4 + kw;
            As[(ml << 6) + (k_l ^ sxm)] = f2bf(v[it]);
        }
        asm volatile("s_waitcnt vmcnt(0)" ::: "memory");
        __syncthreads();
#pragma unroll
        for (int kk = 0; kk < 2; ++kk) {
            bf16x8 a[4], bb[4];
#pragma unroll
            for (int f = 0; f < 4; ++f) {
                int pa = (((f * 16 + (lane & 15)) << 7) + kk * 64 + ((lane >> 4) << 4)) ^ sx;
                int pb = (((w * 64 + f * 16 + (lane & 15)) << 7) + kk * 64 + ((lane >> 4) << 4)) ^ sx;
                a[f]  = *(const bf16x8*)((const char*)As + pa);
                bb[f] = *(const bf16x8*)((const char*)Bs + pb);
            }
#pragma unroll
            for (int fr = 0; fr < 4; ++fr)
#pragma unroll
                for (int fc = 0; fc < 4; ++fc)
                    acc[fr][fc] = __builtin_amdgcn_mfma_f32_16x16x32_bf16(a[fr], bb[fc], acc[fr][fc], 0, 0, 0);
        }
        __syncthreads();
    }

#pragma unroll
    for (int fc = 0; fc < 4; ++fc) {
        const int o = w * 64 + fc * 16 + (lane & 15);
        const float sc = scsh[o], sh = scsh[256 + o];
#pragma unroll
        for (int fr = 0; fr < 4; ++fr) {
            const int mrow = mt * 64 + fr * 16 + (lane >> 4) * 4;
            const int q = mrow >> 2;
            const int bi = q / PP;
            const int node = noff + (q - bi * PP);
            float sum = 0.f;
#pragma unroll
            for (int r = 0; r < 4; ++r)
                sum += fmaxf(acc[fr][fc][r] * sc + sh, 0.f);
            ca.h0out[((size_t)(bi * NODES + node)) * 256 + o] = f2bf(sum * 0.25f);
        }
    }
}

// ---------------------------------------------------------------------------
// Fused GNN layer, BM=32 (525 blocks), gather software-pipelined.
// ---------------------------------------------------------------------------
__global__ __launch_bounds__(256)
void gnn_fused(const unsigned short* __restrict__ h, const unsigned short* __restrict__ BT,
               const float* __restrict__ bias, unsigned short* __restrict__ out, int hier)
{
    __shared__ __align__(16) unsigned short As[32 * 64];   // swizzled, 4 KB
    __shared__ __align__(16) unsigned short Bs[256 * 64];  // swizzled, 32 KB
    const int t = threadIdx.x, lane = t & 63, w = t >> 6;
    const int r0 = blockIdx.x << 5;
    const int myrow = t >> 3, q = t & 7;      // 8 threads per row, 8 k each
    const int grow = r0 + myrow;              // 16800 = 525*32
    const int b = grow / NODES;
    const int n = grow - b * NODES;

    int gw, off;
    if (n < 1600)      { gw = 40; off = 0; }
    else if (n < 2000) { gw = 20; off = 1600; }
    else               { gw = 10; off = 2000; }
    const int li = (n - off) / gw;
    const int lj = (n - off) - li * gw;
    int nbr[9]; int cnt = 0;
    if (!hier) {
#pragma unroll
        for (int di = -1; di <= 1; ++di)
#pragma unroll
            for (int dj = -1; dj <= 1; ++dj) {
                int ii = li + di, jj = lj + dj;
                if (ii >= 0 && ii < gw && jj >= 0 && jj < gw) nbr[cnt++] = off + ii * gw + jj;
            }
    } else {
        nbr[cnt++] = n;
        if (off == 0) {
            nbr[cnt++] = 1600 + (li >> 1) * 20 + (lj >> 1);
        } else if (off == 1600) {
            nbr[cnt++] = 2000 + (li >> 1) * 10 + (lj >> 1);
#pragma unroll
            for (int di = 0; di < 2; ++di)
#pragma unroll
                for (int dj = 0; dj < 2; ++dj)
                    nbr[cnt++] = ((li << 1) + di) * 40 + ((lj << 1) + dj);
        } else {
#pragma unroll
            for (int di = 0; di < 2; ++di)
#pragma unroll
                for (int dj = 0; dj < 2; ++dj)
                    nbr[cnt++] = 1600 + ((li << 1) + di) * 20 + ((lj << 1) + dj);
        }
    }
    int nboff[9];
#pragma unroll
    for (int e = 0; e < 9; ++e)
        nboff[e] = (b * NODES + nbr[e < cnt ? e : 0]) * 256 + q * 8;
    const float inv = 1.0f / (float)cnt;
    const int sx = (lane & 7) << 4;
    const int awr = (myrow << 6) + ((q ^ (myrow & 7)) << 3);  // swizzled write slot

    f32x4 acc[2][4];
#pragma unroll
    for (int fr = 0; fr < 2; ++fr)
#pragma unroll
        for (int fc = 0; fc < 4; ++fc) acc[fr][fc] = (f32x4){0.f, 0.f, 0.f, 0.f};

    // prefetch gather for k0 = 0
    u16x8 pre[9];
#pragma unroll
    for (int e = 0; e < 9; ++e) pre[e] = *(const u16x8*)(h + nboff[e]);

    for (int k0 = 0; k0 < 256; k0 += 64) {
        // B stage (weights, swizzled source)
#pragma unroll
        for (int it = 0; it < 8; ++it) {
            int LO = ((it << 8) + t) << 4;
            int row = LO >> 7;
            int kb = (LO & 127) ^ ((row & 7) << 4);
            gload16(BT + (size_t)row * 256 + k0 + (kb >> 1), (char*)Bs + LO);
        }
        // accumulate current prefetched gather (static indexing, predicated)
        float sacc[8] = {0, 0, 0, 0, 0, 0, 0, 0};
#pragma unroll
        for (int e = 0; e < 9; ++e) {
            if (e < cnt) {
#pragma unroll
                for (int jj = 0; jj < 8; ++jj) sacc[jj] += bf2f(pre[e][jj]);
            }
        }
        u16x8 o0;
#pragma unroll
        for (int jj = 0; jj < 8; ++jj) o0[jj] = f2bf(sacc[jj] * inv);
        *(u16x8*)&As[awr] = o0;

        asm volatile("s_waitcnt vmcnt(0)" ::: "memory");   // drains B-stage glds only
        __syncthreads();

        // prefetch next k-step's gather; in flight during MFMA
        const int k0n = (k0 + 64) & 255;
#pragma unroll
        for (int e = 0; e < 9; ++e) pre[e] = *(const u16x8*)(h + nboff[e] + k0n);

#pragma unroll
        for (int kk = 0; kk < 2; ++kk) {
            bf16x8 a[2], bb[4];
#pragma unroll
            for (int f = 0; f < 2; ++f) {
                int pa = (((f * 16 + (lane & 15)) << 7) + kk * 64 + ((lane >> 4) << 4)) ^ sx;
                a[f] = *(const bf16x8*)((const char*)As + pa);
            }
#pragma unroll
            for (int f = 0; f < 4; ++f) {
                int pb = (((w * 64 + f * 16 + (lane & 15)) << 7) + kk * 64 + ((lane >> 4) << 4)) ^ sx;
                bb[f] = *(const bf16x8*)((const char*)Bs + pb);
            }
#pragma unroll
            for (int fr = 0; fr < 2; ++fr)
#pragma unroll
                for (int fc = 0; fc < 4; ++fc)
                    acc[fr][fc] = __builtin_amdgcn_mfma_f32_16x16x32_bf16(a[fr], bb[fc], acc[fr][fc], 0, 0, 0);
        }
        __syncthreads();
    }

#pragma unroll
    for (int fc = 0; fc < 4; ++fc) {
        const int d = w * 64 + fc * 16 + (lane & 15);
        const float bv = bias[d];
#pragma unroll
        for (int fr = 0; fr < 2; ++fr) {
            int rb = r0 + fr * 16 + (lane >> 4) * 4;
#pragma unroll
            for (int r = 0; r < 4; ++r)
                out[(size_t)(rb + r) * 256 + d] = f2bf(fmaxf(acc[fr][fc][r] + bv, 0.f));
        }
    }
}

// ---------------------------------------------------------------------------
// convT A-matrix build: a[m][c] = h0 + h6 (+ h6[parent]), bf16.  ONE launch.
// ---------------------------------------------------------------------------
__global__ __launch_bounds__(256)
void a_build(const unsigned short* __restrict__ h0, const unsigned short* __restrict__ h6,
             unsigned short* __restrict__ Ao)
{
    int bx = blockIdx.x;
    int P, H2, noff, pbase, pw, haspar; size_t aoff;
    if (bx < 1600)      { P = 1600; H2 = 40; noff = 0;    pbase = 1600; pw = 20; haspar = 1; aoff = 0; }
    else if (bx < 2000) { P = 400;  H2 = 20; noff = 1600; pbase = 2000; pw = 10; haspar = 1; aoff = 12800ULL * 256; bx -= 1600; }
    else                { P = 100;  H2 = 10; noff = 2000; pbase = 0;    pw = 0;  haspar = 0; aoff = 16000ULL * 256; bx -= 2000; }
    const int gid = bx * 256 + threadIdx.x;
    const int m = gid >> 5, c0 = (gid & 31) << 3;
    const int b = m / P, pix = m - b * P;
    const size_t src = ((size_t)(b * NODES + noff + pix)) * 256 + c0;
    u16x8 x0 = *(const u16x8*)(h0 + src);
    u16x8 x6 = *(const u16x8*)(h6 + src);
    float v[8];
#pragma unroll
    for (int e = 0; e < 8; ++e) v[e] = bf2f(x0[e]) + bf2f(x6[e]);
    if (haspar) {
        int ii = pix / H2, jj = pix - ii * H2;
        size_t sp = ((size_t)(b * NODES + pbase + (ii >> 1) * pw + (jj >> 1))) * 256 + c0;
        u16x8 xp = *(const u16x8*)(h6 + sp);
#pragma unroll
        for (int e = 0; e < 8; ++e) v[e] += bf2f(xp[e]);
    }
    u16x8 r;
#pragma unroll
    for (int e = 0; e < 8; ++e) r[e] = f2bf(v[e]);
    *(u16x8*)(Ao + aoff + (size_t)m * 256 + c0) = r;
}

// ---------------------------------------------------------------------------
// convT2x2, 64x64 tiles for occupancy/MLP (+ feat0 copy on 1024 blocks,
// 5-deep unrolled).  Role-swapped: A = tW^T rows, B = pixel rows.
// ---------------------------------------------------------------------------
struct ConvtArgs {
    const unsigned short* WT[3];
    const unsigned short* Apix[3];
    const float* tb[3];
    const float* feat[3];
    float* out[3];
    const float4* cps; float4* cpd;
};

__global__ __launch_bounds__(256)
void convt_fused(ConvtArgs ct)
{
    __shared__ __align__(16) unsigned short As[4096], Bs[4096];   // 8 KB each
    int bx = blockIdx.x;
    if (bx < 1024) {
        // feat0 copy: 13107200 quads = 1024 blk x 256 thr x 50, 5-deep MLP
        const int base = bx * 256 + threadIdx.x;
        const int stride = 1024 * 256;
        const float4* s = ct.cps;
        float4* d = ct.cpd;
        for (int j = 0; j < 50; j += 5) {
            float4 v0 = s[base + (size_t)(j + 0) * stride];
            float4 v1 = s[base + (size_t)(j + 1) * stride];
            float4 v2 = s[base + (size_t)(j + 2) * stride];
            float4 v3 = s[base + (size_t)(j + 3) * stride];
            float4 v4 = s[base + (size_t)(j + 4) * stride];
            d[base + (size_t)(j + 0) * stride] = v0;
            d[base + (size_t)(j + 1) * stride] = v1;
            d[base + (size_t)(j + 2) * stride] = v2;
            d[base + (size_t)(j + 3) * stride] = v3;
            d[base + (size_t)(j + 4) * stride] = v4;
        }
        return;
    }
    bx -= 1024;
    // s0: 200 px-tiles x 32 my-tiles; s1: 50 x 64; s2: 13 x 128 (my fast)
    int s, px, my;
    if (bx < 6400)      { s = 0; px = bx >> 5; my = bx & 31; }
    else if (bx < 9600) { s = 1; bx -= 6400; px = bx >> 6; my = bx & 63; }
    else                { s = 2; bx -= 9600; px = bx >> 7; my = bx & 127; }
    const int Pc[3]  = {1600, 400, 100};
    const int H2c[3] = {40, 20, 10};
    const int Cc[3]  = {512, 1024, 2048};
    const int Mc[3]  = {12800, 3200, 800};
    const int P = Pc[s], H2 = H2c[s], Cout = Cc[s], Mpix = Mc[s];
    const int m0 = my << 6, n0 = px << 6;
    const unsigned short* WT = ct.WT[s];
    const unsigned short* Apix = ct.Apix[s];
    const int nClamp = Mpix - 1;

    const int t = threadIdx.x, lane = t & 63, w = t >> 6;
    const int wr = w >> 1, wc = w & 1;
    const int sx = (lane & 7) << 4;

    f32x4 acc[2][2];
#pragma unroll
    for (int fr = 0; fr < 2; ++fr)
#pragma unroll
        for (int fc = 0; fc < 2; ++fc) acc[fr][fc] = (f32x4){0.f, 0.f, 0.f, 0.f};

    for (int k0 = 0; k0 < 256; k0 += 64) {
#pragma unroll
        for (int i = 0; i < 2; ++i) {
            int LO  = ((i << 8) + t) << 4;          // 0..8191
            int row = LO >> 7;                      // 0..63
            int kb  = (LO & 127) ^ ((row & 7) << 4);
            int ke  = kb >> 1;
            int rb = n0 + row; if (rb > nClamp) rb = nClamp;
            gload16(WT  + (size_t)(m0 + row) * 256 + k0 + ke, (char*)As + LO);
            gload16(Apix + (size_t)rb * 256 + k0 + ke, (char*)Bs + LO);
        }
        asm volatile("s_waitcnt vmcnt(0)" ::: "memory");
        __syncthreads();
#pragma unroll
        for (int kk = 0; kk < 2; ++kk) {
            bf16x8 a[2], bb[2];
#pragma unroll
            for (int f = 0; f < 2; ++f) {
                int pa = (((wr * 32 + f * 16 + (lane & 15)) << 7) + kk * 64 + ((lane >> 4) << 4)) ^ sx;
                int pb = (((wc * 32 + f * 16 + (lane & 15)) << 7) + kk * 64 + ((lane >> 4) << 4)) ^ sx;
                a[f]  = *(const bf16x8*)((const char*)As + pa);
                bb[f] = *(const bf16x8*)((const char*)Bs + pb);
            }
#pragma unroll
            for (int fr = 0; fr < 2; ++fr)
#pragma unroll
                for (int fc = 0; fc < 2; ++fc)
                    acc[fr][fc] = __builtin_amdgcn_mfma_f32_16x16x32_bf16(a[fr], bb[fc], acc[fr][fc], 0, 0, 0);
        }
        __syncthreads();
    }

    const int H = H2 * 2;
    const float* feat = ct.feat[s];
    float* out = ct.out[s];
#pragma unroll
    for (int fc = 0; fc < 2; ++fc) {
        const int p_g = n0 + wc * 32 + fc * 16 + (lane & 15);
        if (p_g < Mpix) {
            const int b = p_g / P, pix = p_g - b * P;
            const int ii = pix / H2, jj = pix - ii * H2;
#pragma unroll
            for (int fr = 0; fr < 2; ++fr) {
                const int rb = m0 + wr * 32 + fr * 16 + (lane >> 4) * 4;
                const int o = rb >> 2;
                const float tbo = ct.tb[s][o];
                size_t base = (((size_t)(b * Cout + o)) * H + 2 * ii) * H + 2 * jj;
                float2 f0 = *(const float2*)&feat[base];
                float2 r0v; r0v.x = acc[fr][fc][0] + tbo + f0.x; r0v.y = acc[fr][fc][1] + tbo + f0.y;
                *(float2*)&out[base] = r0v;
                float2 f1 = *(const float2*)&feat[base + H];
                float2 r1v; r1v.x = acc[fr][fc][2] + tbo + f1.x; r1v.y = acc[fr][fc][3] + tbo + f1.y;
                *(float2*)&out[base + H] = r1v;
            }
        }
    }
}

// ---------------------------------------------------------------------------
extern "C" void kernel_launch(void* const* d_in, const int* in_sizes, int n_in,
                              void* d_out, int out_size, void* d_ws, size_t ws_size,
                              hipStream_t stream)
{
    const float* feats[3] = { (const float*)d_in[1], (const float*)d_in[2], (const float*)d_in[3] };
    const float* gb[6];
    for (int l = 0; l < 6; ++l) gb[l] = (const float*)d_in[23 + 2 * l];
    const float* tb[3] = { (const float*)d_in[35], (const float*)d_in[37], (const float*)d_in[39] };

    // ---- workspace layout ----
    size_t off = 0;
    auto alloc = [&](size_t bytes) { size_t r = off; off = (off + bytes + 511) & ~(size_t)511; return r; };
    unsigned short* h0b  = (unsigned short*)((char*)d_ws + alloc(16800ULL * 256 * 2));
    unsigned short* hA   = (unsigned short*)((char*)d_ws + alloc(16800ULL * 256 * 2));
    unsigned short* hB   = (unsigned short*)((char*)d_ws + alloc(16800ULL * 256 * 2));
    unsigned short* dwb  = (unsigned short*)((char*)d_ws + alloc(917504ULL * 2));
    unsigned short* gWTb = (unsigned short*)((char*)d_ws + alloc(6ULL * 65536 * 2));
    unsigned short* tWTb = (unsigned short*)((char*)d_ws + alloc(3670016ULL * 2));
    float*          scshb= (float*)((char*)d_ws + alloc(3ULL * 512 * 4));
    unsigned short* Aconvt = (unsigned short*)((char*)d_ws + off);   // 8.6 MB

    // ---- mega-prep ----
    PrepArgs pa;
    pa.dw0 = (const float*)d_in[4];  pa.dw1 = (const float*)d_in[10]; pa.dw2 = (const float*)d_in[16];
    pa.gw0 = (const float*)d_in[22]; pa.gw1 = (const float*)d_in[24]; pa.gw2 = (const float*)d_in[26];
    pa.gw3 = (const float*)d_in[28]; pa.gw4 = (const float*)d_in[30]; pa.gw5 = (const float*)d_in[32];
    pa.tw0 = (const float*)d_in[34]; pa.tw1 = (const float*)d_in[36]; pa.tw2 = (const float*)d_in[38];
    pa.g0 = (const float*)d_in[6];  pa.g1 = (const float*)d_in[12]; pa.g2 = (const float*)d_in[18];
    pa.b0 = (const float*)d_in[7];  pa.b1 = (const float*)d_in[13]; pa.b2 = (const float*)d_in[19];
    pa.m0 = (const float*)d_in[8];  pa.m1 = (const float*)d_in[14]; pa.m2 = (const float*)d_in[20];
    pa.v0 = (const float*)d_in[9];  pa.v1 = (const float*)d_in[15]; pa.v2 = (const float*)d_in[21];
    pa.db0 = (const float*)d_in[5]; pa.db1 = (const float*)d_in[11]; pa.db2 = (const float*)d_in[17];
    pa.dwb = dwb; pa.gWTb = gWTb; pa.tWTb = tWTb; pa.scshb = scshb;
    mega_prep<<<dim3(4417), dim3(256), 0, stream>>>(pa);

    // ---- fused conv1x1 ----
    ConvArgs ca;
    ca.feat[0] = feats[0]; ca.feat[1] = feats[1]; ca.feat[2] = feats[2];
    ca.dwb[0] = dwb; ca.dwb[1] = dwb + 131072; ca.dwb[2] = dwb + 393216;
    ca.scsh[0] = scshb; ca.scsh[1] = scshb + 512; ca.scsh[2] = scshb + 1024;
    ca.h0out = h0b;
    conv_fused<<<dim3(1050), dim3(256), 0, stream>>>(ca);

    // ---- 6 fused GNN layers ----
    const int types[6] = {0, 0, 1, 1, 0, 0};
    const unsigned short* hin = h0b;
    unsigned short* houts[6] = {hA, hB, hA, hB, hA, hB};
    for (int l = 0; l < 6; ++l) {
        gnn_fused<<<dim3(525), dim3(256), 0, stream>>>(
            hin, gWTb + (size_t)l * 65536, gb[l], houts[l], types[l]);
        hin = houts[l];
    }
    unsigned short* h6 = hB;

    // ---- convT phase ----
    a_build<<<dim3(2100), dim3(256), 0, stream>>>(h0b, h6, Aconvt);

    ConvtArgs ct;
    ct.WT[0] = tWTb; ct.WT[1] = tWTb + 524288; ct.WT[2] = tWTb + 1572864;
    ct.Apix[0] = Aconvt; ct.Apix[1] = Aconvt + 12800ULL * 256; ct.Apix[2] = Aconvt + 16000ULL * 256;
    ct.tb[0] = tb[0]; ct.tb[1] = tb[1]; ct.tb[2] = tb[2];
    ct.feat[0] = feats[0]; ct.feat[1] = feats[1]; ct.feat[2] = feats[2];
    ct.out[0] = (float*)d_out + 52428800;
    ct.out[1] = (float*)d_out + 52428800 + 26214400;
    ct.out[2] = (float*)d_out + 52428800 + 26214400 + 13107200;
    ct.cps = (const float4*)d_in[0];
    ct.cpd = (float4*)d_out;
    convt_fused<<<dim3(1024 + 11264), dim3(256), 0, stream>>>(ct);
}